// Round 16
// baseline (861.016 us; speedup 1.0000x reference)
//
#include <hip/hip_runtime.h>
#include <hip/hip_fp16.h>
#include <math.h>

#define DIM 64
#define NG 64
#define CIN 192
#define HID 128
#define NCONV 3
#define TB 2048
#define CUTOFF 12.0f
#define EPS 1e-5f
#define SCB 256

typedef int i2v __attribute__((ext_vector_type(2)));
typedef int i4v __attribute__((ext_vector_type(4)));

__device__ __forceinline__ float sp_(float y) {
    return fmaxf(y, 0.f) + __logf(1.f + __expf(-fabsf(y)));
}
__device__ __forceinline__ float sig_(float y) {
    return 1.f / (1.f + __expf(-y));
}
__device__ __forceinline__ float2 h2f2_bits(int bits) {
    __half2 h;
    __builtin_memcpy(&h, &bits, 4);
    return __half22float2(h);
}
__device__ __forceinline__ int f2h2_bits(float a, float b) {
    __half2 h;
    h.x = __float2half(a);
    h.y = __float2half(b);
    int r;
    __builtin_memcpy(&r, &h, 4);
    return r;
}

// Tp[l][i][d] = half2( R_l(x_i)[d], R_l(x_{i+1})[d] );  1.57 MB -> L2-resident.
// Also zeroes stats (768 doubles) and cnt[N] (folds 2 memset dispatches).
__global__ void k_tables(const float* __restrict__ W1, __half2* __restrict__ Tp,
                         double* __restrict__ stats, int* __restrict__ cnt, int N) {
    int gtid = blockIdx.x * 64 + threadIdx.x;
    if (gtid < NCONV * 3 * 128) stats[gtid] = 0.0;
    if (gtid < N) cnt[gtid] = 0;

    int row = blockIdx.x;
    int l = row / TB, i = row % TB;
    int d = threadIdx.x;
    const float stepmu = CUTOFF / (float)(NG - 1);
    const float coeff = -0.5f / (stepmu * stepmu);
    const float stepx = CUTOFF / (float)(TB - 1);
    float x0 = (float)i * stepx;
    float x1 = fminf((float)(i + 1), (float)(TB - 1)) * stepx;
    __shared__ float r0[NG];
    __shared__ float r1[NG];
    float mu = (float)d * stepmu;
    float d0 = x0 - mu, d1 = x1 - mu;
    r0[d] = expf(coeff * d0 * d0);
    r1[d] = expf(coeff * d1 * d1);
    __syncthreads();
    const float* w = W1 + (size_t)(l * CIN + 2 * DIM) * DIM;
    float a0 = 0.f, a1 = 0.f;
#pragma unroll 8
    for (int g = 0; g < NG; ++g) {
        float wv = w[g * DIM + d];
        a0 += r0[g] * wv;
        a1 += r1[g] * wv;
    }
    __half2 hh;
    hh.x = __float2half(a0);
    hh.y = __float2half(a1);
    Tp[(size_t)row * DIM + d] = hh;
}

// ---- CSR build ----
__global__ void k_hist(const int* __restrict__ dst, int* __restrict__ cnt,
                       int* __restrict__ rank, int E) {
    for (int e = blockIdx.x * blockDim.x + threadIdx.x; e < E;
         e += gridDim.x * blockDim.x)
        rank[e] = atomicAdd(&cnt[dst[e]], 1);
}

__global__ void k_scanA(const int* __restrict__ cnt, int* __restrict__ bsum, int N) {
    __shared__ int lds[SCB];
    int i = blockIdx.x * SCB + threadIdx.x;
    lds[threadIdx.x] = (i < N) ? cnt[i] : 0;
    __syncthreads();
    for (int o = SCB / 2; o > 0; o >>= 1) {
        if (threadIdx.x < o) lds[threadIdx.x] += lds[threadIdx.x + o];
        __syncthreads();
    }
    if (threadIdx.x == 0) bsum[blockIdx.x] = lds[0];
}

__global__ void k_scanB(const int* __restrict__ bsum, int* __restrict__ bexcl, int NB) {
    __shared__ int lds[SCB];
    int t = threadIdx.x;
    int v = (t < NB) ? bsum[t] : 0;
    lds[t] = v;
    __syncthreads();
    for (int o = 1; o < SCB; o <<= 1) {
        int add = (t >= o) ? lds[t - o] : 0;
        __syncthreads();
        lds[t] += add;
        __syncthreads();
    }
    if (t < NB) bexcl[t] = lds[t] - v;
}

__global__ void k_scanC(const int* __restrict__ cnt, const int* __restrict__ bexcl,
                        int* __restrict__ off, int N, int E) {
    __shared__ int lds[SCB];
    int t = threadIdx.x;
    int i = blockIdx.x * SCB + t;
    int v = (i < N) ? cnt[i] : 0;
    lds[t] = v;
    __syncthreads();
    for (int o = 1; o < SCB; o <<= 1) {
        int add = (t >= o) ? lds[t - o] : 0;
        __syncthreads();
        lds[t] += add;
        __syncthreads();
    }
    if (i < N) {
        off[i] = bexcl[blockIdx.x] + lds[t] - v;
        if (i == N - 1) off[N] = E;
    }
}

// scatter edges into dst-sorted order: pos = off[dst] + rank (NO atomic).
__global__ void k_scatter(const int* __restrict__ src, const int* __restrict__ dst,
                          const float* __restrict__ dist, const int* __restrict__ off,
                          const int* __restrict__ rank, i4v* __restrict__ es4, int E) {
    const float inv_step = (float)(TB - 1) / CUTOFF;
    for (int e = blockIdx.x * blockDim.x + threadIdx.x; e < E;
         e += gridDim.x * blockDim.x) {
        int t = dst[e];
        int pos = off[t] + rank[e];
        i4v r;
        r.x = src[e];
        r.y = __float_as_int(dist[e] * inv_step);
        r.z = t;
        r.w = 0;
        __builtin_nontemporal_store(r, es4 + pos);
    }
}

// Fused node-state + P/Q kernel, 4-node unroll.
template <int FIRST>
__global__ void __launch_bounds__(256) k_pq(
        const int* __restrict__ at, const float* __restrict__ emb,
        float* __restrict__ node, const float* __restrict__ agg,
        const double* __restrict__ st, const float* __restrict__ g3,
        const float* __restrict__ bt3, double invN,
        const float* __restrict__ W1, const float* __restrict__ b1, int l,
        __half* __restrict__ P16, float* __restrict__ Q, int N) {
    __shared__ float wa[DIM * DIM];
    __shared__ float wb[DIM * DIM];
    const float* WA = W1 + (size_t)(l * CIN) * DIM;
    for (int k = threadIdx.x; k < DIM * DIM; k += blockDim.x) {
        wa[k] = WA[k];
        wb[k] = WA[DIM * DIM + k];
    }
    int lane = threadIdx.x & 63, w = threadIdx.x >> 6;
    float bv = b1[lane];
    float a3 = 0.f, c3 = 0.f;
    if (!FIRST) {
        double m = st[lane] * invN;
        double v = st[64 + lane] * invN - m * m;
        a3 = g3[lane] / sqrtf((float)v + EPS);
        c3 = bt3[lane] - a3 * (float)m;
    }
    __syncthreads();
    int wpb = blockDim.x >> 6;
    int gw = blockIdx.x * wpb + w, nw = gridDim.x * wpb;
    for (int n4 = gw * 4; n4 < N; n4 += nw * 4) {
        float nv[4];
#pragma unroll
        for (int u = 0; u < 4; ++u) {
            int n = n4 + u;
            if (n < N) {
                if (FIRST) nv[u] = emb[at[n] * DIM + lane];
                else nv[u] = node[n * DIM + lane] + a3 * agg[n * DIM + lane] + c3;
                node[n * DIM + lane] = nv[u];
            } else {
                nv[u] = 0.f;
            }
        }
        float ap[4] = {0.f, 0.f, 0.f, 0.f};
        float aq[4] = {bv, bv, bv, bv};
#pragma unroll 4
        for (int k = 0; k < DIM; ++k) {
            float wav = wa[k * DIM + lane];
            float wbv = wb[k * DIM + lane];
#pragma unroll
            for (int u = 0; u < 4; ++u) {
                float b = __shfl(nv[u], k);
                ap[u] += b * wav;
                aq[u] += b * wbv;
            }
        }
#pragma unroll
        for (int u = 0; u < 4; ++u) {
            int n = n4 + u;
            if (n < N) {
                P16[n * DIM + lane] = __float2half(ap[u]);
                Q[n * DIM + lane] = aq[u];
            }
        }
    }
}

// Pass A, EDGE-MAJOR, 4x unrolled: 4 slots x 4 edges = 16 edges/wave-iteration.
__global__ void __launch_bounds__(256) k_convAf(
        const i4v* __restrict__ es4,
        const __half* __restrict__ P16, const float* __restrict__ Q,
        const __half2* __restrict__ Tp,
        double* __restrict__ stats, __half* __restrict__ z16, int E) {
    int lane = threadIdx.x & 63;
    int w = threadIdx.x >> 6;
    int dg = lane & 15, slot = lane >> 4;
    int d0 = dg * 4;
    float s0[4] = {0.f, 0.f, 0.f, 0.f};
    float s1[4] = {0.f, 0.f, 0.f, 0.f};
    int gw = blockIdx.x * 4 + w, nw = gridDim.x * 4;
    for (int eb = gw * 16; eb < E; eb += nw * 16) {
        int e[4];
        bool v[4];
        i4v ev[4];
#pragma unroll
        for (int u = 0; u < 4; ++u) {
            e[u] = eb + slot + u * 4;
            v[u] = (e[u] < E);
            ev[u] = es4[v[u] ? e[u] : E - 1];
        }
        i2v pb[4];
        i4v tb[4];
        float4 q4[4];
        float fr[4];
#pragma unroll
        for (int u = 0; u < 4; ++u) {
            float uu = __int_as_float(ev[u].y);
            int i = (int)uu;
            i = max(0, min(i, TB - 2));
            fr[u] = uu - (float)i;
            pb[u] = *(const i2v*)(P16 + (size_t)ev[u].x * DIM + d0);
            tb[u] = *(const i4v*)(Tp + (size_t)i * DIM + d0);
            q4[u] = *(const float4*)(Q + (size_t)ev[u].z * DIM + d0);
        }
#pragma unroll
        for (int u = 0; u < 4; ++u) {
            float2 p01 = h2f2_bits(pb[u].x), p23 = h2f2_bits(pb[u].y);
            float2 t0 = h2f2_bits(tb[u].x), t1 = h2f2_bits(tb[u].y);
            float2 t2 = h2f2_bits(tb[u].z), t3 = h2f2_bits(tb[u].w);
            float z0 = p01.x + t0.x + fr[u] * (t0.y - t0.x) + q4[u].x;
            float z1 = p01.y + t1.x + fr[u] * (t1.y - t1.x) + q4[u].y;
            float z2 = p23.x + t2.x + fr[u] * (t2.y - t2.x) + q4[u].z;
            float z3 = p23.y + t3.x + fr[u] * (t3.y - t3.x) + q4[u].w;
            if (v[u]) {
                i2v zz;
                zz.x = f2h2_bits(z0, z1);
                zz.y = f2h2_bits(z2, z3);
                *(i2v*)(z16 + (size_t)e[u] * DIM + d0) = zz;
                s0[0] += z0; s1[0] += z0 * z0;
                s0[1] += z1; s1[1] += z1 * z1;
                s0[2] += z2; s1[2] += z2 * z2;
                s0[3] += z3; s1[3] += z3 * z3;
            }
        }
    }
    __shared__ float r0[4][64][4];
    __shared__ float r1[4][64][4];
#pragma unroll
    for (int q = 0; q < 4; ++q) {
        r0[w][lane][q] = s0[q];
        r1[w][lane][q] = s1[q];
    }
    __syncthreads();
    if (threadIdx.x < 64) {
        int d = threadIdx.x;
        int dgg = d >> 2, q = d & 3;
        float t0 = 0.f, t1 = 0.f;
#pragma unroll
        for (int ww = 0; ww < 4; ++ww)
#pragma unroll
            for (int sl = 0; sl < 4; ++sl) {
                t0 += r0[ww][sl * 16 + dgg][q];
                t1 += r1[ww][sl * 16 + dgg][q];
            }
        atomicAdd(&stats[d], (double)t0);
        atomicAdd(&stats[64 + d], (double)t1);
    }
}

// Pass B: flat streaming over z16; f = sigmoid(bn1(z)); stats(f); in-place f16.
__global__ void __launch_bounds__(256) k_statsF(
        __half* __restrict__ zf16,
        const double* __restrict__ stA, const float* __restrict__ gA,
        const float* __restrict__ btA,
        double* __restrict__ stats, int total8, double invE) {
    int gq = threadIdx.x & 7;
    float a1[8], c1[8];
#pragma unroll
    for (int q = 0; q < 8; ++q) {
        int d = gq * 8 + q;
        double m = stA[d] * invE;
        double v = stA[64 + d] * invE - m * m;
        a1[q] = gA[d] / sqrtf((float)v + EPS);
        c1[q] = btA[d] - a1[q] * (float)m;
    }
    float s0[8] = {0, 0, 0, 0, 0, 0, 0, 0};
    float s1[8] = {0, 0, 0, 0, 0, 0, 0, 0};
    i4v* z4 = (i4v*)zf16;
    int tid = blockIdx.x * blockDim.x + threadIdx.x;
    int stride = gridDim.x * blockDim.x;
    for (int i = tid; i < total8; i += stride) {
        i4v v = z4[i];
        float2 p0 = h2f2_bits(v.x);
        float2 p1 = h2f2_bits(v.y);
        float2 p2 = h2f2_bits(v.z);
        float2 p3 = h2f2_bits(v.w);
        float f0 = sig_(a1[0] * p0.x + c1[0]);
        float f1 = sig_(a1[1] * p0.y + c1[1]);
        float f2 = sig_(a1[2] * p1.x + c1[2]);
        float f3 = sig_(a1[3] * p1.y + c1[3]);
        float f4 = sig_(a1[4] * p2.x + c1[4]);
        float f5 = sig_(a1[5] * p2.y + c1[5]);
        float f6 = sig_(a1[6] * p3.x + c1[6]);
        float f7 = sig_(a1[7] * p3.y + c1[7]);
        i4v o;
        o.x = f2h2_bits(f0, f1);
        o.y = f2h2_bits(f2, f3);
        o.z = f2h2_bits(f4, f5);
        o.w = f2h2_bits(f6, f7);
        z4[i] = o;
        s0[0] += f0; s1[0] += f0 * f0;
        s0[1] += f1; s1[1] += f1 * f1;
        s0[2] += f2; s1[2] += f2 * f2;
        s0[3] += f3; s1[3] += f3 * f3;
        s0[4] += f4; s1[4] += f4 * f4;
        s0[5] += f5; s1[5] += f5 * f5;
        s0[6] += f6; s1[6] += f6 * f6;
        s0[7] += f7; s1[7] += f7 * f7;
    }
    __shared__ float lds[256][16];
#pragma unroll
    for (int q = 0; q < 8; ++q) {
        lds[threadIdx.x][q] = s0[q];
        lds[threadIdx.x][8 + q] = s1[q];
    }
    __syncthreads();
    if (threadIdx.x < 64) {
        int d = threadIdx.x;
        int grp = d >> 3, j = d & 7;
        float t0 = 0.f, t1 = 0.f;
        for (int k = 0; k < 32; ++k) {
            int t = k * 8 + grp;
            t0 += lds[t][j];
            t1 += lds[t][8 + j];
        }
        atomicAdd(&stats[d], (double)t0);
        atomicAdd(&stats[64 + d], (double)t1);
    }
}

// Pass C: CSR read of f16; h = f*softplus(bn2(f)); segment reduce -> agg + stats.
// Wave-uniform skip of the B half-chunk when the node's remaining degree <= 8
// (eliminates ~half the padding waste in the softplus pipeline).
__global__ void __launch_bounds__(256) k_aggF(
        const int* __restrict__ off, const __half* __restrict__ f16,
        const double* __restrict__ stB, const float* __restrict__ gB,
        const float* __restrict__ btB,
        double* __restrict__ stats, float* __restrict__ agg, int N, double invE) {
    int lane = threadIdx.x & 63;
    int w = threadIdx.x >> 6;
    int dg = lane & 7, slot = lane >> 3;
    int d0 = dg * 8;
    float a2[8], c2[8];
#pragma unroll
    for (int q = 0; q < 8; ++q) {
        int d = d0 + q;
        double m = stB[d] * invE, v = stB[64 + d] * invE - m * m;
        a2[q] = gB[d] / sqrtf((float)v + EPS);
        c2[q] = btB[d] - a2[q] * (float)m;
    }
    float s0[8] = {0, 0, 0, 0, 0, 0, 0, 0};
    float s1[8] = {0, 0, 0, 0, 0, 0, 0, 0};
    int gw = blockIdx.x * 4 + w, nw = gridDim.x * 4;
    for (int n = gw; n < N; n += nw) {
        int e0 = off[n], e1 = off[n + 1];
        float tot[8] = {0, 0, 0, 0, 0, 0, 0, 0};
        for (int eb = e0; eb < e1; eb += 16) {
            {   // A half: edges eb+slot (at least one valid by loop condition)
                int eA = eb + slot;
                float mkA = (eA < e1) ? 1.f : 0.f;
                int ecA = (eA < e1) ? eA : (e1 - 1);
                i4v zbA = *(const i4v*)(f16 + (size_t)ecA * DIM + d0);
                float2 a0 = h2f2_bits(zbA.x), a1v = h2f2_bits(zbA.y);
                float2 a2v = h2f2_bits(zbA.z), a3v = h2f2_bits(zbA.w);
                float fA[8] = {a0.x, a0.y, a1v.x, a1v.y, a2v.x, a2v.y, a3v.x, a3v.y};
#pragma unroll
                for (int q = 0; q < 8; ++q) {
                    float hA = fA[q] * sp_(a2[q] * fA[q] + c2[q]);
                    tot[q] += mkA * hA;
                }
            }
            if (eb + 8 < e1) {   // B half: wave-uniform skip when degree tail <= 8
                int eB = eb + 8 + slot;
                float mkB = (eB < e1) ? 1.f : 0.f;
                int ecB = (eB < e1) ? eB : (e1 - 1);
                i4v zbB = *(const i4v*)(f16 + (size_t)ecB * DIM + d0);
                float2 b0 = h2f2_bits(zbB.x), b1v = h2f2_bits(zbB.y);
                float2 b2v = h2f2_bits(zbB.z), b3v = h2f2_bits(zbB.w);
                float fB[8] = {b0.x, b0.y, b1v.x, b1v.y, b2v.x, b2v.y, b3v.x, b3v.y};
#pragma unroll
                for (int q = 0; q < 8; ++q) {
                    float hB = fB[q] * sp_(a2[q] * fB[q] + c2[q]);
                    tot[q] += mkB * hB;
                }
            }
        }
#pragma unroll
        for (int q = 0; q < 8; ++q) {
            float v = tot[q];
            v += __shfl_xor(v, 8);
            v += __shfl_xor(v, 16);
            v += __shfl_xor(v, 32);
            tot[q] = v;
        }
        if (slot == 0) {
            float4 w0 = make_float4(tot[0], tot[1], tot[2], tot[3]);
            float4 w1 = make_float4(tot[4], tot[5], tot[6], tot[7]);
            *(float4*)(agg + (size_t)n * DIM + d0) = w0;
            *(float4*)(agg + (size_t)n * DIM + d0 + 4) = w1;
#pragma unroll
            for (int q = 0; q < 8; ++q) {
                s0[q] += tot[q];
                s1[q] += tot[q] * tot[q];
            }
        }
    }
    __shared__ float r0[4][8][8];
    __shared__ float r1[4][8][8];
    if (slot == 0) {
#pragma unroll
        for (int q = 0; q < 8; ++q) {
            r0[w][dg][q] = s0[q];
            r1[w][dg][q] = s1[q];
        }
    }
    __syncthreads();
    if (threadIdx.x < 64) {
        int d = threadIdx.x;
        int dgg = d >> 3, q = d & 7;
        float t0 = 0.f, t1 = 0.f;
#pragma unroll
        for (int ww = 0; ww < 4; ++ww) {
            t0 += r0[ww][dgg][q];
            t1 += r1[ww][dgg][q];
        }
        atomicAdd(&stats[d], (double)t0);
        atomicAdd(&stats[64 + d], (double)t1);
    }
}

// per-graph mean pool of bn3-updated node (bn3 folded in) + softplus + MLP head
__global__ void k_head(const float* __restrict__ node, const float* __restrict__ agg,
                       const double* __restrict__ st, const float* __restrict__ g3,
                       const float* __restrict__ bt3, double invN,
                       const int* __restrict__ gid, int N,
                       const float* __restrict__ Wfc, const float* __restrict__ bfc,
                       const float* __restrict__ Wout, const float* __restrict__ bout,
                       float* __restrict__ out) {
    int g = blockIdx.x;
    __shared__ int bounds[2];
    if (threadIdx.x == 0) {
        int lo = 0, hi = N;
        while (lo < hi) { int mid = (lo + hi) >> 1; if (gid[mid] < g) lo = mid + 1; else hi = mid; }
        bounds[0] = lo;
        int lo2 = lo; hi = N;
        while (lo2 < hi) { int mid = (lo2 + hi) >> 1; if (gid[mid] < g + 1) lo2 = mid + 1; else hi = mid; }
        bounds[1] = lo2;
    }
    __syncthreads();
    int s = bounds[0], e = bounds[1];
    __shared__ float sp[DIM];
    if (threadIdx.x < DIM) {
        int d = threadIdx.x;
        double mm = st[d] * invN;
        double vv = st[64 + d] * invN - mm * mm;
        float a3 = g3[d] / sqrtf((float)vv + EPS);
        float c3 = bt3[d] - a3 * (float)mm;
        float sn = 0.f, sa = 0.f;
        for (int n = s; n < e; ++n) {
            sn += node[(size_t)n * DIM + d];
            sa += agg[(size_t)n * DIM + d];
        }
        float cntf = (float)max(e - s, 1);
        float m = (sn + a3 * sa) / cntf + c3;
        sp[d] = (m > 0.f) ? m + log1pf(expf(-m)) : log1pf(expf(m));
    }
    __syncthreads();
    int j = threadIdx.x;
    float hj = bfc[j];
#pragma unroll 8
    for (int k = 0; k < DIM; ++k) hj += sp[k] * Wfc[k * HID + j];
    hj = (hj > 0.f) ? hj + log1pf(expf(-hj)) : log1pf(expf(hj));
    __shared__ float red[HID];
    red[j] = hj * Wout[j];
    __syncthreads();
    for (int o = HID / 2; o > 0; o >>= 1) {
        if (j < o) red[j] += red[j + o];
        __syncthreads();
    }
    if (j == 0) out[g] = red[0] + bout[0];
}

// ---------------- fallback (no z16 buffer): recompute passes ----------------
template <int MODE>
__global__ void __launch_bounds__(256) k_conv(
        const int* __restrict__ off, const i4v* __restrict__ es4,
        const __half* __restrict__ P16, const float* __restrict__ Q,
        const __half2* __restrict__ Tp,
        const double* __restrict__ stA, const float* __restrict__ gA,
        const float* __restrict__ btA,
        const double* __restrict__ stB, const float* __restrict__ gB,
        const float* __restrict__ btB,
        double* __restrict__ stats, float* __restrict__ agg, int N, double invE) {
    int lane = threadIdx.x & 63;
    int w = threadIdx.x >> 6;
    float a1 = 0.f, c1 = 0.f, a2 = 0.f, c2 = 0.f;
    if (MODE >= 2) {
        double m = stA[lane] * invE;
        double v = stA[64 + lane] * invE - m * m;
        a1 = gA[lane] / sqrtf((float)v + EPS);
        c1 = btA[lane] - a1 * (float)m;
    }
    if (MODE == 3) {
        double m = stB[lane] * invE;
        double v = stB[64 + lane] * invE - m * m;
        a2 = gB[lane] / sqrtf((float)v + EPS);
        c2 = btB[lane] - a2 * (float)m;
    }
    float s0 = 0.f, s1 = 0.f;
    int gw = blockIdx.x * 4 + w, nw = gridDim.x * 4;
    for (int n = gw; n < N; n += nw) {
        int e0 = off[n], e1 = off[n + 1];
        float qc = Q[n * DIM + lane];
        float acc = 0.f;
        auto body = [&](i4v ev) {
            float u = __int_as_float(ev.y);
            int i = (int)u;
            i = max(0, min(i, TB - 2));
            float fr = u - (float)i;
            float2 t2 = __half22float2(Tp[(size_t)i * DIM + lane]);
            float p = __half2float(P16[(size_t)ev.x * DIM + lane]);
            float z = p + t2.x + fr * (t2.y - t2.x) + qc;
            if (MODE == 0) { s0 += z; s1 += z * z; }
            else {
                float f = sig_(a1 * z + c1);
                if (MODE == 2) { s0 += f; s1 += f * f; }
                else acc += f * sp_(a2 * f + c2);
            }
        };
        int e = e0;
        for (; e + 2 <= e1; e += 2) { body(es4[e]); body(es4[e + 1]); }
        if (e < e1) body(es4[e]);
        if (MODE == 3) {
            agg[n * DIM + lane] = acc;
            s0 += acc; s1 += acc * acc;
        }
    }
    __shared__ float r0[4][64];
    __shared__ float r1[4][64];
    r0[w][lane] = s0;
    r1[w][lane] = s1;
    __syncthreads();
    if (threadIdx.x < 64) {
        int d = threadIdx.x;
        float t0 = r0[0][d] + r0[1][d] + r0[2][d] + r0[3][d];
        float t1 = r1[0][d] + r1[1][d] + r1[2][d] + r1[3][d];
        atomicAdd(&stats[d], (double)t0);
        atomicAdd(&stats[64 + d], (double)t1);
    }
}

extern "C" void kernel_launch(void* const* d_in, const int* in_sizes, int n_in,
                              void* d_out, int out_size, void* d_ws, size_t ws_size,
                              hipStream_t stream) {
    const int* atom_types = (const int*)d_in[0];
    const int* src = (const int*)d_in[1];
    const int* dst = (const int*)d_in[2];
    const int* gid = (const int*)d_in[3];
    const float* dist = (const float*)d_in[4];
    const float* emb = (const float*)d_in[5];
    const float* W1 = (const float*)d_in[6];
    const float* b1 = (const float*)d_in[7];
    // d_in[8]=W2, d_in[9]=b2: dead (reference bug: fc_full2 output unused)
    const float* g1 = (const float*)d_in[10];
    const float* bt1 = (const float*)d_in[11];
    const float* g2 = (const float*)d_in[12];
    const float* bt2 = (const float*)d_in[13];
    const float* g3 = (const float*)d_in[14];
    const float* bt3 = (const float*)d_in[15];
    const float* Wfc = (const float*)d_in[16];
    const float* bfc = (const float*)d_in[17];
    const float* Wout = (const float*)d_in[18];
    const float* bout = (const float*)d_in[19];

    int N = in_sizes[0];
    int E = in_sizes[1];
    int G = out_size;
    int NB = (N + SCB - 1) / SCB;   // <= 256 for N <= 65536

    char* ws = (char*)d_ws;
    auto alloc = [&](size_t bytes) -> char* {
        char* p = ws;
        ws += (bytes + 255) & ~(size_t)255;
        return p;
    };
    size_t nd = (size_t)N * DIM * sizeof(float);
    float* node = (float*)alloc(nd);
    __half* P16 = (__half*)alloc(nd / 2);
    float* Q = (float*)alloc(nd);
    float* agg = (float*)alloc(nd);
    __half2* Tp = (__half2*)alloc((size_t)NCONV * TB * DIM * sizeof(__half2));
    double* stats = (double*)alloc((size_t)NCONV * 3 * 128 * sizeof(double));
    int* off = (int*)alloc((size_t)(N + 1) * sizeof(int));
    int* cnt = (int*)alloc((size_t)N * sizeof(int));
    int* bsum = (int*)alloc(SCB * sizeof(int));
    int* bexcl = (int*)alloc(SCB * sizeof(int));
    int* rank = (int*)alloc((size_t)E * sizeof(int));
    i4v* es4 = (i4v*)alloc((size_t)E * sizeof(i4v));
    size_t zbytes = (size_t)E * DIM * sizeof(__half);
    size_t used = (size_t)(ws - (char*)d_ws);
    bool planZ = (used + zbytes) <= ws_size;
    __half* z16 = planZ ? (__half*)alloc(zbytes) : nullptr;

    // k_tables also zeroes stats + cnt (folds two memset dispatches)
    k_tables<<<NCONV * TB, 64, 0, stream>>>(W1, Tp, stats, cnt, N);
    k_hist<<<1024, 256, 0, stream>>>(dst, cnt, rank, E);
    k_scanA<<<NB, SCB, 0, stream>>>(cnt, bsum, N);
    k_scanB<<<1, SCB, 0, stream>>>(bsum, bexcl, NB);
    k_scanC<<<NB, SCB, 0, stream>>>(cnt, bexcl, off, N, E);
    k_scatter<<<1024, 256, 0, stream>>>(src, dst, dist, off, rank, es4, E);

    double invE = 1.0 / (double)E;
    double invN = 1.0 / (double)N;

    for (int l = 0; l < NCONV; ++l) {
        const __half2* Tl = Tp + (size_t)l * TB * DIM;
        double* st1 = stats + (size_t)(l * 3 + 0) * 128;
        double* st2 = stats + (size_t)(l * 3 + 1) * 128;
        double* st3 = stats + (size_t)(l * 3 + 2) * 128;

        if (l == 0) {
            k_pq<1><<<2048, 256, 0, stream>>>(atom_types, emb, node, nullptr,
                                              nullptr, nullptr, nullptr, 0.0,
                                              W1, b1 + l * DIM, l, P16, Q, N);
        } else {
            double* st3p = stats + (size_t)((l - 1) * 3 + 2) * 128;
            k_pq<0><<<2048, 256, 0, stream>>>(atom_types, emb, node, agg,
                                              st3p, g3 + (l - 1) * DIM,
                                              bt3 + (l - 1) * DIM, invN,
                                              W1, b1 + l * DIM, l, P16, Q, N);
        }

        if (planZ) {
            k_convAf<<<2048, 256, 0, stream>>>(es4, P16, Q, Tl, st1, z16, E);
            k_statsF<<<2048, 256, 0, stream>>>(z16, st1, g1 + l * DIM, bt1 + l * DIM,
                                               st2, E * 8, invE);
            k_aggF<<<2048, 256, 0, stream>>>(off, z16,
                                             st2, g2 + l * DIM, bt2 + l * DIM,
                                             st3, agg, N, invE);
        } else {
            k_conv<0><<<2048, 256, 0, stream>>>(off, es4, P16, Q, Tl,
                                                nullptr, nullptr, nullptr,
                                                nullptr, nullptr, nullptr,
                                                st1, nullptr, N, invE);
            k_conv<2><<<2048, 256, 0, stream>>>(off, es4, P16, Q, Tl,
                                                st1, g1 + l * DIM, bt1 + l * DIM,
                                                nullptr, nullptr, nullptr,
                                                st2, nullptr, N, invE);
            k_conv<3><<<2048, 256, 0, stream>>>(off, es4, P16, Q, Tl,
                                                st1, g1 + l * DIM, bt1 + l * DIM,
                                                st2, g2 + l * DIM, bt2 + l * DIM,
                                                st3, agg, N, invE);
        }
    }

    double* st3f = stats + (size_t)(2 * 3 + 2) * 128;
    k_head<<<G, HID, 0, stream>>>(node, agg, st3f, g3 + 2 * DIM, bt3 + 2 * DIM,
                                  invN, gid, N, Wfc, bfc, Wout, bout, (float*)d_out);
}

// Round 17
// 854.464 us; speedup vs baseline: 1.0077x; 1.0077x over previous
//
#include <hip/hip_runtime.h>
#include <hip/hip_fp16.h>
#include <math.h>

#define DIM 64
#define NG 64
#define CIN 192
#define HID 128
#define NCONV 3
#define TB 2048
#define CUTOFF 12.0f
#define EPS 1e-5f
#define SCB 256

typedef int i2v __attribute__((ext_vector_type(2)));
typedef int i4v __attribute__((ext_vector_type(4)));

__device__ __forceinline__ float sp_(float y) {
    return fmaxf(y, 0.f) + __logf(1.f + __expf(-fabsf(y)));
}
__device__ __forceinline__ float sig_(float y) {
    return 1.f / (1.f + __expf(-y));
}
__device__ __forceinline__ float2 h2f2_bits(int bits) {
    __half2 h;
    __builtin_memcpy(&h, &bits, 4);
    return __half22float2(h);
}
__device__ __forceinline__ int f2h2_bits(float a, float b) {
    __half2 h;
    h.x = __float2half(a);
    h.y = __float2half(b);
    int r;
    __builtin_memcpy(&r, &h, 4);
    return r;
}

// Tp[l][i][d] = half2( R_l(x_i)[d], R_l(x_{i+1})[d] );  1.57 MB -> L2-resident.
// Also zeroes stats (768 doubles) and cnt[N] (folds 2 memset dispatches).
__global__ void k_tables(const float* __restrict__ W1, __half2* __restrict__ Tp,
                         double* __restrict__ stats, int* __restrict__ cnt, int N) {
    int gtid = blockIdx.x * 64 + threadIdx.x;
    if (gtid < NCONV * 3 * 128) stats[gtid] = 0.0;
    if (gtid < N) cnt[gtid] = 0;

    int row = blockIdx.x;
    int l = row / TB, i = row % TB;
    int d = threadIdx.x;
    const float stepmu = CUTOFF / (float)(NG - 1);
    const float coeff = -0.5f / (stepmu * stepmu);
    const float stepx = CUTOFF / (float)(TB - 1);
    float x0 = (float)i * stepx;
    float x1 = fminf((float)(i + 1), (float)(TB - 1)) * stepx;
    __shared__ float r0[NG];
    __shared__ float r1[NG];
    float mu = (float)d * stepmu;
    float d0 = x0 - mu, d1 = x1 - mu;
    r0[d] = expf(coeff * d0 * d0);
    r1[d] = expf(coeff * d1 * d1);
    __syncthreads();
    const float* w = W1 + (size_t)(l * CIN + 2 * DIM) * DIM;
    float a0 = 0.f, a1 = 0.f;
#pragma unroll 8
    for (int g = 0; g < NG; ++g) {
        float wv = w[g * DIM + d];
        a0 += r0[g] * wv;
        a1 += r1[g] * wv;
    }
    __half2 hh;
    hh.x = __float2half(a0);
    hh.y = __float2half(a1);
    Tp[(size_t)row * DIM + d] = hh;
}

// ---- CSR build ----
__global__ void k_hist(const int* __restrict__ dst, int* __restrict__ cnt,
                       int* __restrict__ rank, int E) {
    for (int e = blockIdx.x * blockDim.x + threadIdx.x; e < E;
         e += gridDim.x * blockDim.x)
        rank[e] = atomicAdd(&cnt[dst[e]], 1);
}

__global__ void k_scanA(const int* __restrict__ cnt, int* __restrict__ bsum, int N) {
    __shared__ int lds[SCB];
    int i = blockIdx.x * SCB + threadIdx.x;
    lds[threadIdx.x] = (i < N) ? cnt[i] : 0;
    __syncthreads();
    for (int o = SCB / 2; o > 0; o >>= 1) {
        if (threadIdx.x < o) lds[threadIdx.x] += lds[threadIdx.x + o];
        __syncthreads();
    }
    if (threadIdx.x == 0) bsum[blockIdx.x] = lds[0];
}

// fused: each block computes its own bsum prefix (reduce over t < blockIdx.x),
// then the intra-block exclusive scan of cnt. (scanB dispatch eliminated)
__global__ void k_scanC(const int* __restrict__ cnt, const int* __restrict__ bsum,
                        int* __restrict__ off, int N, int E, int NB) {
    __shared__ int lds[SCB];
    __shared__ int bex;
    int t = threadIdx.x;
    int v = (t < NB && t < (int)blockIdx.x) ? bsum[t] : 0;
    lds[t] = v;
    __syncthreads();
    for (int o = SCB / 2; o > 0; o >>= 1) {
        if (t < o) lds[t] += lds[t + o];
        __syncthreads();
    }
    if (t == 0) bex = lds[0];
    __syncthreads();
    int i = blockIdx.x * SCB + t;
    int c = (i < N) ? cnt[i] : 0;
    lds[t] = c;
    __syncthreads();
    for (int o = 1; o < SCB; o <<= 1) {
        int add = (t >= o) ? lds[t - o] : 0;
        __syncthreads();
        lds[t] += add;
        __syncthreads();
    }
    if (i < N) {
        off[i] = bex + lds[t] - c;
        if (i == N - 1) off[N] = E;
    }
}

// scatter edges into dst-sorted order: pos = off[dst] + rank (NO atomic).
__global__ void k_scatter(const int* __restrict__ src, const int* __restrict__ dst,
                          const float* __restrict__ dist, const int* __restrict__ off,
                          const int* __restrict__ rank, i4v* __restrict__ es4, int E) {
    const float inv_step = (float)(TB - 1) / CUTOFF;
    for (int e = blockIdx.x * blockDim.x + threadIdx.x; e < E;
         e += gridDim.x * blockDim.x) {
        int t = dst[e];
        int pos = off[t] + rank[e];
        i4v r;
        r.x = src[e];
        r.y = __float_as_int(dist[e] * inv_step);
        r.z = t;
        r.w = 0;
        __builtin_nontemporal_store(r, es4 + pos);
    }
}

// Fused node-state + P/Q kernel, 4-node unroll.
template <int FIRST>
__global__ void __launch_bounds__(256) k_pq(
        const int* __restrict__ at, const float* __restrict__ emb,
        float* __restrict__ node, const float* __restrict__ agg,
        const double* __restrict__ st, const float* __restrict__ g3,
        const float* __restrict__ bt3, double invN,
        const float* __restrict__ W1, const float* __restrict__ b1, int l,
        __half* __restrict__ P16, float* __restrict__ Q, int N) {
    __shared__ float wa[DIM * DIM];
    __shared__ float wb[DIM * DIM];
    const float* WA = W1 + (size_t)(l * CIN) * DIM;
    for (int k = threadIdx.x; k < DIM * DIM; k += blockDim.x) {
        wa[k] = WA[k];
        wb[k] = WA[DIM * DIM + k];
    }
    int lane = threadIdx.x & 63, w = threadIdx.x >> 6;
    float bv = b1[lane];
    float a3 = 0.f, c3 = 0.f;
    if (!FIRST) {
        double m = st[lane] * invN;
        double v = st[64 + lane] * invN - m * m;
        a3 = g3[lane] / sqrtf((float)v + EPS);
        c3 = bt3[lane] - a3 * (float)m;
    }
    __syncthreads();
    int wpb = blockDim.x >> 6;
    int gw = blockIdx.x * wpb + w, nw = gridDim.x * wpb;
    for (int n4 = gw * 4; n4 < N; n4 += nw * 4) {
        float nv[4];
#pragma unroll
        for (int u = 0; u < 4; ++u) {
            int n = n4 + u;
            if (n < N) {
                if (FIRST) nv[u] = emb[at[n] * DIM + lane];
                else nv[u] = node[n * DIM + lane] + a3 * agg[n * DIM + lane] + c3;
                node[n * DIM + lane] = nv[u];
            } else {
                nv[u] = 0.f;
            }
        }
        float ap[4] = {0.f, 0.f, 0.f, 0.f};
        float aq[4] = {bv, bv, bv, bv};
#pragma unroll 4
        for (int k = 0; k < DIM; ++k) {
            float wav = wa[k * DIM + lane];
            float wbv = wb[k * DIM + lane];
#pragma unroll
            for (int u = 0; u < 4; ++u) {
                float b = __shfl(nv[u], k);
                ap[u] += b * wav;
                aq[u] += b * wbv;
            }
        }
#pragma unroll
        for (int u = 0; u < 4; ++u) {
            int n = n4 + u;
            if (n < N) {
                P16[n * DIM + lane] = __float2half(ap[u]);
                Q[n * DIM + lane] = aq[u];
            }
        }
    }
}

// Pass A, EDGE-MAJOR, 4x unrolled: 4 slots x 4 edges = 16 edges/wave-iteration.
__global__ void __launch_bounds__(256) k_convAf(
        const i4v* __restrict__ es4,
        const __half* __restrict__ P16, const float* __restrict__ Q,
        const __half2* __restrict__ Tp,
        double* __restrict__ stats, __half* __restrict__ z16, int E) {
    int lane = threadIdx.x & 63;
    int w = threadIdx.x >> 6;
    int dg = lane & 15, slot = lane >> 4;
    int d0 = dg * 4;
    float s0[4] = {0.f, 0.f, 0.f, 0.f};
    float s1[4] = {0.f, 0.f, 0.f, 0.f};
    int gw = blockIdx.x * 4 + w, nw = gridDim.x * 4;
    for (int eb = gw * 16; eb < E; eb += nw * 16) {
        int e[4];
        bool v[4];
        i4v ev[4];
#pragma unroll
        for (int u = 0; u < 4; ++u) {
            e[u] = eb + slot + u * 4;
            v[u] = (e[u] < E);
            ev[u] = es4[v[u] ? e[u] : E - 1];
        }
        i2v pb[4];
        i4v tb[4];
        float4 q4[4];
        float fr[4];
#pragma unroll
        for (int u = 0; u < 4; ++u) {
            float uu = __int_as_float(ev[u].y);
            int i = (int)uu;
            i = max(0, min(i, TB - 2));
            fr[u] = uu - (float)i;
            pb[u] = *(const i2v*)(P16 + (size_t)ev[u].x * DIM + d0);
            tb[u] = *(const i4v*)(Tp + (size_t)i * DIM + d0);
            q4[u] = *(const float4*)(Q + (size_t)ev[u].z * DIM + d0);
        }
#pragma unroll
        for (int u = 0; u < 4; ++u) {
            float2 p01 = h2f2_bits(pb[u].x), p23 = h2f2_bits(pb[u].y);
            float2 t0 = h2f2_bits(tb[u].x), t1 = h2f2_bits(tb[u].y);
            float2 t2 = h2f2_bits(tb[u].z), t3 = h2f2_bits(tb[u].w);
            float z0 = p01.x + t0.x + fr[u] * (t0.y - t0.x) + q4[u].x;
            float z1 = p01.y + t1.x + fr[u] * (t1.y - t1.x) + q4[u].y;
            float z2 = p23.x + t2.x + fr[u] * (t2.y - t2.x) + q4[u].z;
            float z3 = p23.y + t3.x + fr[u] * (t3.y - t3.x) + q4[u].w;
            if (v[u]) {
                i2v zz;
                zz.x = f2h2_bits(z0, z1);
                zz.y = f2h2_bits(z2, z3);
                *(i2v*)(z16 + (size_t)e[u] * DIM + d0) = zz;
                s0[0] += z0; s1[0] += z0 * z0;
                s0[1] += z1; s1[1] += z1 * z1;
                s0[2] += z2; s1[2] += z2 * z2;
                s0[3] += z3; s1[3] += z3 * z3;
            }
        }
    }
    __shared__ float r0[4][64][4];
    __shared__ float r1[4][64][4];
#pragma unroll
    for (int q = 0; q < 4; ++q) {
        r0[w][lane][q] = s0[q];
        r1[w][lane][q] = s1[q];
    }
    __syncthreads();
    if (threadIdx.x < 64) {
        int d = threadIdx.x;
        int dgg = d >> 2, q = d & 3;
        float t0 = 0.f, t1 = 0.f;
#pragma unroll
        for (int ww = 0; ww < 4; ++ww)
#pragma unroll
            for (int sl = 0; sl < 4; ++sl) {
                t0 += r0[ww][sl * 16 + dgg][q];
                t1 += r1[ww][sl * 16 + dgg][q];
            }
        atomicAdd(&stats[d], (double)t0);
        atomicAdd(&stats[64 + d], (double)t1);
    }
}

// Pass B: flat streaming over z16; f = sigmoid(bn1(z)); stats(f); in-place f16.
__global__ void __launch_bounds__(256) k_statsF(
        __half* __restrict__ zf16,
        const double* __restrict__ stA, const float* __restrict__ gA,
        const float* __restrict__ btA,
        double* __restrict__ stats, int total8, double invE) {
    int gq = threadIdx.x & 7;
    float a1[8], c1[8];
#pragma unroll
    for (int q = 0; q < 8; ++q) {
        int d = gq * 8 + q;
        double m = stA[d] * invE;
        double v = stA[64 + d] * invE - m * m;
        a1[q] = gA[d] / sqrtf((float)v + EPS);
        c1[q] = btA[d] - a1[q] * (float)m;
    }
    float s0[8] = {0, 0, 0, 0, 0, 0, 0, 0};
    float s1[8] = {0, 0, 0, 0, 0, 0, 0, 0};
    i4v* z4 = (i4v*)zf16;
    int tid = blockIdx.x * blockDim.x + threadIdx.x;
    int stride = gridDim.x * blockDim.x;
    for (int i = tid; i < total8; i += stride) {
        i4v v = z4[i];
        float2 p0 = h2f2_bits(v.x);
        float2 p1 = h2f2_bits(v.y);
        float2 p2 = h2f2_bits(v.z);
        float2 p3 = h2f2_bits(v.w);
        float f0 = sig_(a1[0] * p0.x + c1[0]);
        float f1 = sig_(a1[1] * p0.y + c1[1]);
        float f2 = sig_(a1[2] * p1.x + c1[2]);
        float f3 = sig_(a1[3] * p1.y + c1[3]);
        float f4 = sig_(a1[4] * p2.x + c1[4]);
        float f5 = sig_(a1[5] * p2.y + c1[5]);
        float f6 = sig_(a1[6] * p3.x + c1[6]);
        float f7 = sig_(a1[7] * p3.y + c1[7]);
        i4v o;
        o.x = f2h2_bits(f0, f1);
        o.y = f2h2_bits(f2, f3);
        o.z = f2h2_bits(f4, f5);
        o.w = f2h2_bits(f6, f7);
        z4[i] = o;
        s0[0] += f0; s1[0] += f0 * f0;
        s0[1] += f1; s1[1] += f1 * f1;
        s0[2] += f2; s1[2] += f2 * f2;
        s0[3] += f3; s1[3] += f3 * f3;
        s0[4] += f4; s1[4] += f4 * f4;
        s0[5] += f5; s1[5] += f5 * f5;
        s0[6] += f6; s1[6] += f6 * f6;
        s0[7] += f7; s1[7] += f7 * f7;
    }
    __shared__ float lds[256][16];
#pragma unroll
    for (int q = 0; q < 8; ++q) {
        lds[threadIdx.x][q] = s0[q];
        lds[threadIdx.x][8 + q] = s1[q];
    }
    __syncthreads();
    if (threadIdx.x < 64) {
        int d = threadIdx.x;
        int grp = d >> 3, j = d & 7;
        float t0 = 0.f, t1 = 0.f;
        for (int k = 0; k < 32; ++k) {
            int t = k * 8 + grp;
            t0 += lds[t][j];
            t1 += lds[t][8 + j];
        }
        atomicAdd(&stats[d], (double)t0);
        atomicAdd(&stats[64 + d], (double)t1);
    }
}

// Pass C: CSR read of f16; h = f*softplus(bn2(f)); segment reduce -> agg + stats.
// (round-15 form: measured-best)
__global__ void __launch_bounds__(256) k_aggF(
        const int* __restrict__ off, const __half* __restrict__ f16,
        const double* __restrict__ stB, const float* __restrict__ gB,
        const float* __restrict__ btB,
        double* __restrict__ stats, float* __restrict__ agg, int N, double invE) {
    int lane = threadIdx.x & 63;
    int w = threadIdx.x >> 6;
    int dg = lane & 7, slot = lane >> 3;
    int d0 = dg * 8;
    float a2[8], c2[8];
#pragma unroll
    for (int q = 0; q < 8; ++q) {
        int d = d0 + q;
        double m = stB[d] * invE, v = stB[64 + d] * invE - m * m;
        a2[q] = gB[d] / sqrtf((float)v + EPS);
        c2[q] = btB[d] - a2[q] * (float)m;
    }
    float s0[8] = {0, 0, 0, 0, 0, 0, 0, 0};
    float s1[8] = {0, 0, 0, 0, 0, 0, 0, 0};
    int gw = blockIdx.x * 4 + w, nw = gridDim.x * 4;
    for (int n = gw; n < N; n += nw) {
        int e0 = off[n], e1 = off[n + 1];
        float tot[8] = {0, 0, 0, 0, 0, 0, 0, 0};
        for (int eb = e0; eb < e1; eb += 16) {
            int eA = eb + slot, eB = eA + 8;
            float mkA = (eA < e1) ? 1.f : 0.f;
            float mkB = (eB < e1) ? 1.f : 0.f;
            int ecA = (eA < e1) ? eA : (e1 - 1);
            int ecB = (eB < e1) ? eB : (e1 - 1);
            i4v zbA = *(const i4v*)(f16 + (size_t)ecA * DIM + d0);
            i4v zbB = *(const i4v*)(f16 + (size_t)ecB * DIM + d0);
            float2 a0 = h2f2_bits(zbA.x), a1v = h2f2_bits(zbA.y);
            float2 a2v = h2f2_bits(zbA.z), a3v = h2f2_bits(zbA.w);
            float2 b0 = h2f2_bits(zbB.x), b1v = h2f2_bits(zbB.y);
            float2 b2v = h2f2_bits(zbB.z), b3v = h2f2_bits(zbB.w);
            float fA[8] = {a0.x, a0.y, a1v.x, a1v.y, a2v.x, a2v.y, a3v.x, a3v.y};
            float fB[8] = {b0.x, b0.y, b1v.x, b1v.y, b2v.x, b2v.y, b3v.x, b3v.y};
#pragma unroll
            for (int q = 0; q < 8; ++q) {
                float hA = fA[q] * sp_(a2[q] * fA[q] + c2[q]);
                float hB = fB[q] * sp_(a2[q] * fB[q] + c2[q]);
                tot[q] += mkA * hA + mkB * hB;
            }
        }
#pragma unroll
        for (int q = 0; q < 8; ++q) {
            float v = tot[q];
            v += __shfl_xor(v, 8);
            v += __shfl_xor(v, 16);
            v += __shfl_xor(v, 32);
            tot[q] = v;
        }
        if (slot == 0) {
            float4 w0 = make_float4(tot[0], tot[1], tot[2], tot[3]);
            float4 w1 = make_float4(tot[4], tot[5], tot[6], tot[7]);
            *(float4*)(agg + (size_t)n * DIM + d0) = w0;
            *(float4*)(agg + (size_t)n * DIM + d0 + 4) = w1;
#pragma unroll
            for (int q = 0; q < 8; ++q) {
                s0[q] += tot[q];
                s1[q] += tot[q] * tot[q];
            }
        }
    }
    __shared__ float r0[4][8][8];
    __shared__ float r1[4][8][8];
    if (slot == 0) {
#pragma unroll
        for (int q = 0; q < 8; ++q) {
            r0[w][dg][q] = s0[q];
            r1[w][dg][q] = s1[q];
        }
    }
    __syncthreads();
    if (threadIdx.x < 64) {
        int d = threadIdx.x;
        int dgg = d >> 3, q = d & 7;
        float t0 = 0.f, t1 = 0.f;
#pragma unroll
        for (int ww = 0; ww < 4; ++ww) {
            t0 += r0[ww][dgg][q];
            t1 += r1[ww][dgg][q];
        }
        atomicAdd(&stats[d], (double)t0);
        atomicAdd(&stats[64 + d], (double)t1);
    }
}

// per-graph mean pool of bn3-updated node (bn3 folded in) + softplus + MLP head
__global__ void k_head(const float* __restrict__ node, const float* __restrict__ agg,
                       const double* __restrict__ st, const float* __restrict__ g3,
                       const float* __restrict__ bt3, double invN,
                       const int* __restrict__ gid, int N,
                       const float* __restrict__ Wfc, const float* __restrict__ bfc,
                       const float* __restrict__ Wout, const float* __restrict__ bout,
                       float* __restrict__ out) {
    int g = blockIdx.x;
    __shared__ int bounds[2];
    if (threadIdx.x == 0) {
        int lo = 0, hi = N;
        while (lo < hi) { int mid = (lo + hi) >> 1; if (gid[mid] < g) lo = mid + 1; else hi = mid; }
        bounds[0] = lo;
        int lo2 = lo; hi = N;
        while (lo2 < hi) { int mid = (lo2 + hi) >> 1; if (gid[mid] < g + 1) lo2 = mid + 1; else hi = mid; }
        bounds[1] = lo2;
    }
    __syncthreads();
    int s = bounds[0], e = bounds[1];
    __shared__ float sp[DIM];
    if (threadIdx.x < DIM) {
        int d = threadIdx.x;
        double mm = st[d] * invN;
        double vv = st[64 + d] * invN - mm * mm;
        float a3 = g3[d] / sqrtf((float)vv + EPS);
        float c3 = bt3[d] - a3 * (float)mm;
        float sn = 0.f, sa = 0.f;
        for (int n = s; n < e; ++n) {
            sn += node[(size_t)n * DIM + d];
            sa += agg[(size_t)n * DIM + d];
        }
        float cntf = (float)max(e - s, 1);
        float m = (sn + a3 * sa) / cntf + c3;
        sp[d] = (m > 0.f) ? m + log1pf(expf(-m)) : log1pf(expf(m));
    }
    __syncthreads();
    int j = threadIdx.x;
    float hj = bfc[j];
#pragma unroll 8
    for (int k = 0; k < DIM; ++k) hj += sp[k] * Wfc[k * HID + j];
    hj = (hj > 0.f) ? hj + log1pf(expf(-hj)) : log1pf(expf(hj));
    __shared__ float red[HID];
    red[j] = hj * Wout[j];
    __syncthreads();
    for (int o = HID / 2; o > 0; o >>= 1) {
        if (j < o) red[j] += red[j + o];
        __syncthreads();
    }
    if (j == 0) out[g] = red[0] + bout[0];
}

// ---------------- fallback (no z16 buffer): recompute passes ----------------
template <int MODE>
__global__ void __launch_bounds__(256) k_conv(
        const int* __restrict__ off, const i4v* __restrict__ es4,
        const __half* __restrict__ P16, const float* __restrict__ Q,
        const __half2* __restrict__ Tp,
        const double* __restrict__ stA, const float* __restrict__ gA,
        const float* __restrict__ btA,
        const double* __restrict__ stB, const float* __restrict__ gB,
        const float* __restrict__ btB,
        double* __restrict__ stats, float* __restrict__ agg, int N, double invE) {
    int lane = threadIdx.x & 63;
    int w = threadIdx.x >> 6;
    float a1 = 0.f, c1 = 0.f, a2 = 0.f, c2 = 0.f;
    if (MODE >= 2) {
        double m = stA[lane] * invE;
        double v = stA[64 + lane] * invE - m * m;
        a1 = gA[lane] / sqrtf((float)v + EPS);
        c1 = btA[lane] - a1 * (float)m;
    }
    if (MODE == 3) {
        double m = stB[lane] * invE;
        double v = stB[64 + lane] * invE - m * m;
        a2 = gB[lane] / sqrtf((float)v + EPS);
        c2 = btB[lane] - a2 * (float)m;
    }
    float s0 = 0.f, s1 = 0.f;
    int gw = blockIdx.x * 4 + w, nw = gridDim.x * 4;
    for (int n = gw; n < N; n += nw) {
        int e0 = off[n], e1 = off[n + 1];
        float qc = Q[n * DIM + lane];
        float acc = 0.f;
        auto body = [&](i4v ev) {
            float u = __int_as_float(ev.y);
            int i = (int)u;
            i = max(0, min(i, TB - 2));
            float fr = u - (float)i;
            float2 t2 = __half22float2(Tp[(size_t)i * DIM + lane]);
            float p = __half2float(P16[(size_t)ev.x * DIM + lane]);
            float z = p + t2.x + fr * (t2.y - t2.x) + qc;
            if (MODE == 0) { s0 += z; s1 += z * z; }
            else {
                float f = sig_(a1 * z + c1);
                if (MODE == 2) { s0 += f; s1 += f * f; }
                else acc += f * sp_(a2 * f + c2);
            }
        };
        int e = e0;
        for (; e + 2 <= e1; e += 2) { body(es4[e]); body(es4[e + 1]); }
        if (e < e1) body(es4[e]);
        if (MODE == 3) {
            agg[n * DIM + lane] = acc;
            s0 += acc; s1 += acc * acc;
        }
    }
    __shared__ float r0[4][64];
    __shared__ float r1[4][64];
    r0[w][lane] = s0;
    r1[w][lane] = s1;
    __syncthreads();
    if (threadIdx.x < 64) {
        int d = threadIdx.x;
        float t0 = r0[0][d] + r0[1][d] + r0[2][d] + r0[3][d];
        float t1 = r1[0][d] + r1[1][d] + r1[2][d] + r1[3][d];
        atomicAdd(&stats[d], (double)t0);
        atomicAdd(&stats[64 + d], (double)t1);
    }
}

extern "C" void kernel_launch(void* const* d_in, const int* in_sizes, int n_in,
                              void* d_out, int out_size, void* d_ws, size_t ws_size,
                              hipStream_t stream) {
    const int* atom_types = (const int*)d_in[0];
    const int* src = (const int*)d_in[1];
    const int* dst = (const int*)d_in[2];
    const int* gid = (const int*)d_in[3];
    const float* dist = (const float*)d_in[4];
    const float* emb = (const float*)d_in[5];
    const float* W1 = (const float*)d_in[6];
    const float* b1 = (const float*)d_in[7];
    // d_in[8]=W2, d_in[9]=b2: dead (reference bug: fc_full2 output unused)
    const float* g1 = (const float*)d_in[10];
    const float* bt1 = (const float*)d_in[11];
    const float* g2 = (const float*)d_in[12];
    const float* bt2 = (const float*)d_in[13];
    const float* g3 = (const float*)d_in[14];
    const float* bt3 = (const float*)d_in[15];
    const float* Wfc = (const float*)d_in[16];
    const float* bfc = (const float*)d_in[17];
    const float* Wout = (const float*)d_in[18];
    const float* bout = (const float*)d_in[19];

    int N = in_sizes[0];
    int E = in_sizes[1];
    int G = out_size;
    int NB = (N + SCB - 1) / SCB;   // <= 256 for N <= 65536

    char* ws = (char*)d_ws;
    auto alloc = [&](size_t bytes) -> char* {
        char* p = ws;
        ws += (bytes + 255) & ~(size_t)255;
        return p;
    };
    size_t nd = (size_t)N * DIM * sizeof(float);
    float* node = (float*)alloc(nd);
    __half* P16 = (__half*)alloc(nd / 2);
    float* Q = (float*)alloc(nd);
    float* agg = (float*)alloc(nd);
    __half2* Tp = (__half2*)alloc((size_t)NCONV * TB * DIM * sizeof(__half2));
    double* stats = (double*)alloc((size_t)NCONV * 3 * 128 * sizeof(double));
    int* off = (int*)alloc((size_t)(N + 1) * sizeof(int));
    int* cnt = (int*)alloc((size_t)N * sizeof(int));
    int* bsum = (int*)alloc(SCB * sizeof(int));
    int* rank = (int*)alloc((size_t)E * sizeof(int));
    i4v* es4 = (i4v*)alloc((size_t)E * sizeof(i4v));
    size_t zbytes = (size_t)E * DIM * sizeof(__half);
    size_t used = (size_t)(ws - (char*)d_ws);
    bool planZ = (used + zbytes) <= ws_size;
    __half* z16 = planZ ? (__half*)alloc(zbytes) : nullptr;

    // k_tables also zeroes stats + cnt (folds two memset dispatches)
    k_tables<<<NCONV * TB, 64, 0, stream>>>(W1, Tp, stats, cnt, N);
    k_hist<<<1024, 256, 0, stream>>>(dst, cnt, rank, E);
    k_scanA<<<NB, SCB, 0, stream>>>(cnt, bsum, N);
    k_scanC<<<NB, SCB, 0, stream>>>(cnt, bsum, off, N, E, NB);
    k_scatter<<<1024, 256, 0, stream>>>(src, dst, dist, off, rank, es4, E);

    double invE = 1.0 / (double)E;
    double invN = 1.0 / (double)N;

    for (int l = 0; l < NCONV; ++l) {
        const __half2* Tl = Tp + (size_t)l * TB * DIM;
        double* st1 = stats + (size_t)(l * 3 + 0) * 128;
        double* st2 = stats + (size_t)(l * 3 + 1) * 128;
        double* st3 = stats + (size_t)(l * 3 + 2) * 128;

        if (l == 0) {
            k_pq<1><<<2048, 256, 0, stream>>>(atom_types, emb, node, nullptr,
                                              nullptr, nullptr, nullptr, 0.0,
                                              W1, b1 + l * DIM, l, P16, Q, N);
        } else {
            double* st3p = stats + (size_t)((l - 1) * 3 + 2) * 128;
            k_pq<0><<<2048, 256, 0, stream>>>(atom_types, emb, node, agg,
                                              st3p, g3 + (l - 1) * DIM,
                                              bt3 + (l - 1) * DIM, invN,
                                              W1, b1 + l * DIM, l, P16, Q, N);
        }

        if (planZ) {
            k_convAf<<<2048, 256, 0, stream>>>(es4, P16, Q, Tl, st1, z16, E);
            k_statsF<<<2048, 256, 0, stream>>>(z16, st1, g1 + l * DIM, bt1 + l * DIM,
                                               st2, E * 8, invE);
            k_aggF<<<2048, 256, 0, stream>>>(off, z16,
                                             st2, g2 + l * DIM, bt2 + l * DIM,
                                             st3, agg, N, invE);
        } else {
            k_conv<0><<<2048, 256, 0, stream>>>(off, es4, P16, Q, Tl,
                                                nullptr, nullptr, nullptr,
                                                nullptr, nullptr, nullptr,
                                                st1, nullptr, N, invE);
            k_conv<2><<<2048, 256, 0, stream>>>(off, es4, P16, Q, Tl,
                                                st1, g1 + l * DIM, bt1 + l * DIM,
                                                nullptr, nullptr, nullptr,
                                                st2, nullptr, N, invE);
            k_conv<3><<<2048, 256, 0, stream>>>(off, es4, P16, Q, Tl,
                                                st1, g1 + l * DIM, bt1 + l * DIM,
                                                st2, g2 + l * DIM, bt2 + l * DIM,
                                                st3, agg, N, invE);
        }
    }

    double* st3f = stats + (size_t)(2 * 3 + 2) * 128;
    k_head<<<G, HID, 0, stream>>>(node, agg, st3f, g3 + 2 * DIM, bt3 + 2 * DIM,
                                  invN, gid, N, Wfc, bfc, Wout, bout, (float*)d_out);
}